// Round 6
// baseline (770.776 us; speedup 1.0000x reference)
//
#include <hip/hip_runtime.h>

// LIF scan: B=16, S=256, H=128, N=64. T = S*H = 32768 sequential steps per
// (b,n) chain; 1024 chains. Bit-exactness with the fp32 sequential reference
// required -> add chain cannot be reassociated. Chain form (proven bit-exact
// R6..R12):   s' = prev ? x : fl(s + x);  prev' = s' > th
//
// R13: eliminate the sequential stitch entirely. R10/R11/R12 all failed the
// same way: the compiler dissolves source-level register pipelines
// (VGPR_Count stuck at 132), leaving a serial dependent-load chain ->
// 400-514us. But the proven coalescence property implies something stronger:
// a row that coalesces has exit state (z_end[r], zm[r].bit31) INDEPENDENT of
// its entry. So speculate every row coalesces:
//   A[r] = (z_end[r-1], bit31[r-1]), A[0] = (acc0, false)   -- all parallel.
//  K1z  (4096 waves): z-run each row from fresh state (unchanged, proven).
//  K2v  (4096 waves): validate row r from A[r] with the proven 32-step
//       coalescence check; checkpoint := A[r]; if some lane uncoalesced
//       (P ~ 1e-3), finish 128 steps and store true exit X[r] + dirty flag.
//  K3f  (16 waves, sequential): scan dirty flags (clean -> skip). On dirty:
//       adopt X[r]; while exit != A[r+1], patch checkpoint of next row and
//       re-run it from global x (rare; usually heals in 1 row). Worst case
//       degrades to full sequential re-run -- correct for any data.
//  K4   pass2: BYTE-IDENTICAL to R8..R12 (proven absmax=0).

namespace {
constexpr int kB = 16;
constexpr int kS = 256;
constexpr int kH = 128;
constexpr int kN = 64;
constexpr int kT = kS * kH;                 // 32768
constexpr long kPerB = (long)kS * kN * kH;  // 2,097,152 per batch per tensor
// ws layout: zpack | ckpt_s | ckpt_m | dirt | xend_s | xend_m
constexpr size_t kWsZp = (size_t)kB * kS * kN * 8;                     // 2 MB
constexpr size_t kWsS = (size_t)kB * kS * kN * sizeof(float);          // 1 MB
constexpr size_t kWsM = (size_t)kB * kS * sizeof(unsigned long long);  // 32 KB
constexpr size_t kWsD = (size_t)kB * kS * sizeof(int);                 // 16 KB
constexpr size_t kWsXs = (size_t)kB * kS * kN * sizeof(float);         // 1 MB
constexpr size_t kWsXm = (size_t)kB * kS * sizeof(unsigned long long); // 32 KB
}

typedef float v4f __attribute__((ext_vector_type(4)));
typedef unsigned long long u64;

// Opaque VGPR zero: defeats uniform-scalarization so wave-uniform-looking
// loads use the vector path (vmcnt, in-order) instead of SMEM s_loads
// (lgkmcnt, unordered -> full drains). Proven effective in R6.
__device__ __forceinline__ int opaque_vgpr_zero() {
  int z;
  asm volatile("v_mov_b32 %0, 0" : "=v"(z));
  return z;
}

// ---------------------------------------------------------------------------
// K1z: z-run every (b,row) from the fresh state (prev=true -> step 0 gives
// s = x_0 exactly). Packed result: .x bits0..30 spike@step0..30, bit31 =
// exit prev (step 127); .y = bitcast(exit state). (unchanged, proven)
// ---------------------------------------------------------------------------
__global__ __launch_bounds__(64, 2) void lif_zrun_kernel(
    const float* __restrict__ x, const float* __restrict__ thresh,
    uint2* __restrict__ zpack) {
  const int wid = blockIdx.x;
  const int b = wid >> 8;
  const int srow = wid & 255;
  const int lane = threadIdx.x;

  const v4f* __restrict__ xr4 =
      (const v4f*)(x + (long)b * kT + srow * kH) + opaque_vgpr_zero();
  v4f xb[32];
#pragma unroll
  for (int i = 0; i < 32; ++i) xb[i] = xr4[i];  // 32 loads in flight

  const float th = thresh[lane];
  float s = 0.0f;
  bool prev = true;  // fresh start: step 0 takes s = x_0
  unsigned m = 0;

#pragma unroll
  for (int h = 0; h < kH; ++h) {
    const float xt = xb[h >> 2][h & 3];
    const float u = s + xt;
    s = prev ? xt : u;
    prev = s > th;
    if (h < 31) m |= (unsigned)prev << h;
    if (h == 127) m |= (unsigned)prev << 31;
  }
  uint2 zp;
  zp.x = m;
  zp.y = __float_as_uint(s);
  zpack[((long)b * kS + srow) * kN + lane] = zp;
}

// ---------------------------------------------------------------------------
// K2v: parallel validation. One wave per (b,row). Entry = A[r] (speculative).
// Writes checkpoint = A[r]. Runs the proven coalescence check; dirty rows
// (some lane uncoalesced within the 31-step window) store their true exit.
// ---------------------------------------------------------------------------
__global__ __launch_bounds__(64, 2) void lif_validate_kernel(
    const float* __restrict__ x, const float* __restrict__ thresh,
    const float* __restrict__ acc0, const uint2* __restrict__ zpack,
    float* __restrict__ ckpt_s, u64* __restrict__ ckpt_m,
    int* __restrict__ dirt, float* __restrict__ xend_s,
    u64* __restrict__ xend_m) {
  const int wid = blockIdx.x;
  const int b = wid >> 8;
  const int r = wid & 255;
  const int lane = threadIdx.x;
  const long rowi = (long)b * kS + r;

  // speculative entry A[r]
  float s_in;
  bool p_in;
  if (r == 0) {
    s_in = acc0[b * kN + lane];
    p_in = false;
  } else {
    const uint2 zprev = zpack[(rowi - 1) * kN + lane];
    s_in = __uint_as_float(zprev.y);
    p_in = (zprev.x >> 31) != 0u;
  }
  // checkpoint := A[r] (patched later by fixup iff speculation failed)
  ckpt_s[rowi * kN + lane] = s_in;
  {
    const u64 bm = __ballot(p_in);
    if (lane == 0) ckpt_m[rowi] = bm;
  }

  const uint2 zc = zpack[rowi * kN + lane];
  const unsigned zm = zc.x;
  const float th = thresh[lane];

  const v4f* __restrict__ xr4 =
      (const v4f*)(x + (long)b * kT + r * kH) + opaque_vgpr_zero();
  v4f qa[8];
#pragma unroll
  for (int i = 0; i < 8; ++i) qa[i] = xr4[i];  // first 32 steps

  float srun = s_in;
  bool prun = p_in;
  bool live = !p_in;  // p_in lanes: row IS the z-run from step 0

#pragma unroll
  for (int g = 0; g < 8; ++g) {
#pragma unroll
    for (int j = 0; j < 4; ++j) {
      const int h = 4 * g + j;
      const float xt = qa[g][j];
      const float u = srun + xt;
      srun = prun ? xt : u;
      prun = srun > th;
      if (h < 31) live = live && !(prun && ((zm >> h) & 1u));
    }
  }

  if (__ballot(live) == 0) {
    if (lane == 0) dirt[rowi] = 0;  // clean: exit == A[r+1] by construction
    return;
  }
  // dirty: finish all 128 steps for the live lanes (rare)
  v4f qb[24];
#pragma unroll
  for (int i = 0; i < 24; ++i) qb[i] = xr4[8 + i];
#pragma unroll
  for (int g = 0; g < 24; ++g) {
#pragma unroll
    for (int j = 0; j < 4; ++j) {
      const float xt = qb[g][j];
      const float u = srun + xt;
      srun = prun ? xt : u;
      prun = srun > th;
    }
  }
  const float s_ex = live ? srun : __uint_as_float(zc.y);
  const bool p_ex = live ? prun : ((zc.x >> 31) != 0u);
  xend_s[rowi * kN + lane] = s_ex;
  {
    const u64 xm = __ballot(p_ex);
    if (lane == 0) {
      xend_m[rowi] = xm;
      dirt[rowi] = 1;
    }
  }
}

// ---------------------------------------------------------------------------
// K3f: sequential fixup. One wave per batch. Clean rows: zero work (skip).
// Dirty row r: adopt stored true exit X[r]; while exit != A[r+1], patch the
// next row's checkpoint and re-run it from global x until re-coalescence.
// ---------------------------------------------------------------------------
__global__ __launch_bounds__(64, 1) void lif_fixup_kernel(
    const float* __restrict__ x, const float* __restrict__ thresh,
    const uint2* __restrict__ zpack, const int* __restrict__ dirt,
    const float* __restrict__ xend_s, const u64* __restrict__ xend_m,
    float* __restrict__ ckpt_s, u64* __restrict__ ckpt_m) {
  const int b = blockIdx.x;
  const int lane = threadIdx.x;
  const float th = thresh[lane];

  float s = 0.0f;
  bool p = false;
  bool ok = true;  // true entry of current row == A[r] (speculation holds)

#pragma unroll 1
  for (int r = 0; r < kS; ++r) {
    const long rowi = (long)b * kS + r;
    if (ok) {
      if (dirt[rowi] == 0) continue;  // exit == A[r+1]: nothing to do
      // K2v ran this row from the true entry -> stored X[r] is the truth.
      s = xend_s[rowi * kN + lane];
      p = (xend_m[rowi] >> lane) & 1ULL;
      const uint2 zc = zpack[rowi * kN + lane];
      const bool match =
          (__float_as_uint(s) == zc.y) && (p == ((zc.x >> 31) != 0u));
      ok = __all(match);  // matches A[r+1] -> back on the speculative track
    } else {
      // true entry (s,p) != A[r]: patch checkpoint and re-run this row.
      ckpt_s[rowi * kN + lane] = s;
      {
        const u64 bm = __ballot(p);
        if (lane == 0) ckpt_m[rowi] = bm;
      }
      const uint2 zc = zpack[rowi * kN + lane];
      const unsigned zm = zc.x;
      const v4f* __restrict__ xr4 =
          (const v4f*)(x + (long)b * kT + r * kH) + opaque_vgpr_zero();
      v4f qa[8];
#pragma unroll
      for (int i = 0; i < 8; ++i) qa[i] = xr4[i];
      float srun = s;
      bool prun = p;
      bool live = !p;
#pragma unroll
      for (int g = 0; g < 8; ++g) {
#pragma unroll
        for (int j = 0; j < 4; ++j) {
          const int h = 4 * g + j;
          const float xt = qa[g][j];
          const float u = srun + xt;
          srun = prun ? xt : u;
          prun = srun > th;
          if (h < 31) live = live && !(prun && ((zm >> h) & 1u));
        }
      }
      if (__ballot(live) != 0) {
        v4f qb[24];
#pragma unroll
        for (int i = 0; i < 24; ++i) qb[i] = xr4[8 + i];
#pragma unroll
        for (int g = 0; g < 24; ++g) {
#pragma unroll
          for (int j = 0; j < 4; ++j) {
            const float xt = qb[g][j];
            const float u = srun + xt;
            srun = prun ? xt : u;
            prun = srun > th;
          }
        }
      }
      s = live ? srun : __uint_as_float(zc.y);
      p = live ? prun : ((zc.x >> 31) != 0u);
      const bool match =
          (__float_as_uint(s) == zc.y) && (p == ((zc.x >> 31) != 0u));
      ok = __all(match);
    }
  }
}

// ---------------------------------------------------------------------------
// K4: replay + dense coalesced write (byte-identical to R8..R12 pass2,
// proven absmax = 0). One wave per (b,row); lane = n.
// ---------------------------------------------------------------------------
__global__ __launch_bounds__(64, 2) void lif_pass2_kernel(
    const float* __restrict__ x, const float* __restrict__ thresh,
    const float* __restrict__ ckpt_s, const u64* __restrict__ ckpt_m,
    float* __restrict__ out) {
  const int wid = blockIdx.x;
  const int b = wid >> 8;
  const int srow = wid & 255;
  const int lane = threadIdx.x;

  __shared__ float ov[kH / 2][kN + 1];  // 16.6 KB

  const v4f* __restrict__ xr4 =
      (const v4f*)(x + (long)b * kT + srow * kH) + opaque_vgpr_zero();

  v4f xb[32];
#pragma unroll
  for (int i = 0; i < 32; ++i) xb[i] = xr4[i];  // 32 loads in flight

  const float th = thresh[lane];
  float s = ckpt_s[((long)b * kS + srow) * kN + lane];
  bool prev = (ckpt_m[b * kS + srow] >> lane) & 1ULL;

  float* __restrict__ obase = out + (long)b * kPerB + (long)srow * (kN * kH);
  float* __restrict__ sbase = obase + (long)kB * kPerB;

#pragma unroll
  for (int half = 0; half < 2; ++half) {
#pragma unroll
    for (int hh = 0; hh < kH / 2; ++hh) {
      const int h = half * (kH / 2) + hh;
      const float xt = xb[h >> 2][h & 3];
      const float u = s + xt;
      s = prev ? xt : u;  // bit-identical replay
      prev = s > th;
      ov[hh][lane] = prev ? s : 0.0f;
    }
    const int q = lane & 15;
    const int nsub = lane >> 4;
    const int h0 = half * (kH / 2) + q * 4;
#pragma unroll
    for (int i = 0; i < 16; ++i) {
      const int n = i * 4 + nsub;
      v4f o, sp;
#pragma unroll
      for (int j = 0; j < 4; ++j) {
        const float v = ov[q * 4 + j][n];
        o[j] = v;
        sp[j] = v > 0.0f ? 1.0f : 0.0f;
      }
      *(v4f*)(obase + (long)n * kH + h0) = o;
      *(v4f*)(sbase + (long)n * kH + h0) = sp;
    }
  }
}

// ---------------------------------------------------------------------------
// Fallback A (ws in [1.03MB, 4.3MB)): R8 sequential pass1 + pass2.
// ---------------------------------------------------------------------------
__global__ __launch_bounds__(64, 1) void lif_pass1_kernel(
    const float* __restrict__ x, const float* __restrict__ thresh,
    const float* __restrict__ acc0, float* __restrict__ ckpt_s,
    u64* __restrict__ ckpt_m) {
  const int b = blockIdx.x;
  const int lane = threadIdx.x;
  const float th = thresh[lane];

  __shared__ v4f xs[2048];  // 32 KB: one quarter of this batch's x stream

  const v4f* __restrict__ xg =
      (const v4f*)(x + (long)b * kT) + opaque_vgpr_zero();

  float s = acc0[b * kN + lane];
  bool prev = false;

  float* __restrict__ cs = ckpt_s + (long)b * kS * kN + lane;
  u64* __restrict__ cm = ckpt_m + (long)b * kS;

  for (int q = 0; q < 4; ++q) {
    {
      const v4f* __restrict__ src = xg + (long)q * 2048 + lane;
      v4f tmp[32];
#pragma unroll
      for (int i = 0; i < 32; ++i) tmp[i] = src[i * 64];
#pragma unroll
      for (int i = 0; i < 32; ++i) xs[i * 64 + lane] = tmp[i];
    }
    for (int jrow = 0; jrow < 64; ++jrow) {
      const int r = q * 64 + jrow;
      cs[(long)r * kN] = s;
      {
        const u64 m = __ballot(prev);
        if (lane == 0) cm[r] = m;
      }
      const v4f* __restrict__ xr = &xs[jrow * 32];
#pragma unroll
      for (int k = 0; k < 32; ++k) {
        const v4f xv = xr[k];
#pragma unroll
        for (int j = 0; j < 4; ++j) {
          const float xt = xv[j];
          const float u = s + xt;
          s = prev ? xt : u;
          prev = s > th;
        }
      }
    }
  }
}

// ---------------------------------------------------------------------------
// Fallback B (tiny ws): R4's passing fused kernel (unchanged).
// ---------------------------------------------------------------------------
__global__ __launch_bounds__(128) void lif_fused_kernel(
    const float* __restrict__ x, const float* __restrict__ thresh,
    const float* __restrict__ acc0, float* __restrict__ out) {
  const int bid = blockIdx.x;
  const int b = bid >> 2;
  const int ng = bid & 3;
  const int tid = threadIdx.x;
  const int wave = tid >> 6;
  const int lane = tid & 63;
  __shared__ float buf[2][kH][64];
  const float* __restrict__ xb = x + (long)b * kT;
  float* __restrict__ outs_g = out + (long)b * kPerB + (long)(ng * 16) * kH;
  float* __restrict__ spks_g = outs_g + (long)kB * kPerB;
  if (wave == 0) {
    const int n = lane & 15;
    const float th = thresh[ng * 16 + n];
    float s = acc0[b * kN + ng * 16 + n];
    bool prev = false;
    for (int r = 0; r < kS + 1; ++r) {
      if (r < kS) {
        float* __restrict__ bk = &buf[r & 1][0][lane];
        const float* __restrict__ xr = xb + r * kH;
#pragma unroll
        for (int k = 0; k < kH; ++k) {
          const float xt = xr[k];
          const float u = s + xt;
          s = prev ? xt : u;
          prev = s > th;
          bk[k * 64] = s;
        }
      }
      __syncthreads();
    }
  } else {
    const int n = lane >> 2;
    const int hg = lane & 3;
    const float th = thresh[ng * 16 + n];
    for (int r = 0; r < kS + 1; ++r) {
      if (r > 0) {
        const int rr = r - 1;
        const float(*bk)[64] = buf[rr & 1];
        float* __restrict__ orow = outs_g + (long)rr * (kN * kH) + n * kH;
        float* __restrict__ srow = spks_g + (long)rr * (kN * kH) + n * kH;
#pragma unroll
        for (int i = 0; i < 8; ++i) {
          const int hh = hg * 4 + i * 16;
          v4f ovv, sv;
#pragma unroll
          for (int j = 0; j < 4; ++j) {
            const float v = bk[hh + j][n];
            const bool sp = v > th;
            ovv[j] = sp ? v : 0.0f;
            sv[j] = sp ? 1.0f : 0.0f;
          }
          *(v4f*)(orow + hh) = ovv;
          *(v4f*)(srow + hh) = sv;
        }
      }
      __syncthreads();
    }
  }
}

// ---------------------------------------------------------------------------
extern "C" void kernel_launch(void* const* d_in, const int* in_sizes, int n_in,
                              void* d_out, int out_size, void* d_ws, size_t ws_size,
                              hipStream_t stream) {
  const float* inputs = (const float*)d_in[0];    // [B,S,H] fp32
  const float* threshes = (const float*)d_in[1];  // [N] fp32
  const float* acc0 = (const float*)d_in[2];      // [B,N] fp32
  float* out = (float*)d_out;

  if (ws_size >= kWsZp + kWsS + kWsM + kWsD + kWsXs + kWsXm) {
    char* p = (char*)d_ws;
    uint2* zpackp = (uint2*)p;            p += kWsZp;
    float* ckpt_s = (float*)p;            p += kWsS;
    u64* ckpt_m = (u64*)p;                p += kWsM;
    int* dirt = (int*)p;                  p += kWsD;
    float* xend_s = (float*)p;            p += kWsXs;
    u64* xend_m = (u64*)p;
    lif_zrun_kernel<<<kB * kS, kN, 0, stream>>>(inputs, threshes, zpackp);
    lif_validate_kernel<<<kB * kS, kN, 0, stream>>>(
        inputs, threshes, acc0, zpackp, ckpt_s, ckpt_m, dirt, xend_s, xend_m);
    lif_fixup_kernel<<<kB, kN, 0, stream>>>(inputs, threshes, zpackp, dirt,
                                            xend_s, xend_m, ckpt_s, ckpt_m);
    lif_pass2_kernel<<<kB * kS, kN, 0, stream>>>(inputs, threshes, ckpt_s,
                                                 ckpt_m, out);
  } else if (ws_size >= kWsS + kWsM) {
    float* ckpt_s = (float*)d_ws;
    u64* ckpt_m = (u64*)((char*)d_ws + kWsS);
    lif_pass1_kernel<<<kB, kN, 0, stream>>>(inputs, threshes, acc0, ckpt_s,
                                            ckpt_m);
    lif_pass2_kernel<<<kB * kS, kN, 0, stream>>>(inputs, threshes, ckpt_s,
                                                 ckpt_m, out);
  } else {
    lif_fused_kernel<<<kB * 4, 128, 0, stream>>>(inputs, threshes, acc0, out);
  }
}

// Round 7
// 699.449 us; speedup vs baseline: 1.1020x; 1.1020x over previous
//
#include <hip/hip_runtime.h>

// LIF scan: B=16, S=256, H=128, N=64. T = S*H = 32768 sequential steps per
// (b,n) chain; 1024 chains. Bit-exactness with the fp32 sequential reference
// required -> add chain cannot be reassociated. Chain form (proven bit-exact
// R6..R13):   s' = prev ? x : fl(s + x);  prev' = s' > th
//
// R14: R13's fixup was 508us because "dirty" (some lane live at step 31)
// fired on a large fraction of rows, and each cost the 16-wave fixup 2+
// serial cross-XCD round trips (FETCH 2MB >> the 16KB of flags). Fix:
// dirty != needs-fixing. K2v runs the full 128 steps anyway -> it can check
// exit == A[r+1] itself. Only true MISMATCHES (no coalescence within 128
// steps, P ~1e-5/lane) need the sequential fixup. And with the full run in
// K2v, the 31-bit window mask is dead weight -> zexit = (exit_s, exit_prev).
//  K1z (4096 waves): z-run each row from fresh state -> zexit.
//  K2v (4096 waves): entry A[r] = zexit[r-1] (acc0 at r=0); checkpoint :=
//      A[r]; run 128 steps; dirt := !__all(exit == zexit[r]); store true
//      exit X[r] iff dirt.
//  K3f (16 waves): 4 lane-parallel flag loads + ballots -> 256-bit bitmap
//      in SGPRs; all-clean (virtually always) -> return. Else the proven
//      sequential patch-walk from R13 (correct for any data).
//  K4  pass2: BYTE-IDENTICAL to R8..R13 (proven absmax=0 five times).

namespace {
constexpr int kB = 16;
constexpr int kS = 256;
constexpr int kH = 128;
constexpr int kN = 64;
constexpr int kT = kS * kH;                 // 32768
constexpr long kPerB = (long)kS * kN * kH;  // 2,097,152 per batch per tensor
// ws layout: zexit | ckpt_s | ckpt_m | dirt | xend_s | xend_m  (= R13 sizes)
constexpr size_t kWsZp = (size_t)kB * kS * kN * 8;                     // 2 MB
constexpr size_t kWsS = (size_t)kB * kS * kN * sizeof(float);          // 1 MB
constexpr size_t kWsM = (size_t)kB * kS * sizeof(unsigned long long);  // 32 KB
constexpr size_t kWsD = (size_t)kB * kS * sizeof(int);                 // 16 KB
constexpr size_t kWsXs = (size_t)kB * kS * kN * sizeof(float);         // 1 MB
constexpr size_t kWsXm = (size_t)kB * kS * sizeof(unsigned long long); // 32 KB
}

typedef float v4f __attribute__((ext_vector_type(4)));
typedef unsigned long long u64;

// Opaque VGPR zero: defeats uniform-scalarization so wave-uniform-looking
// loads use the vector path (vmcnt, in-order) instead of SMEM s_loads
// (lgkmcnt, unordered -> full drains). Proven effective in R6.
__device__ __forceinline__ int opaque_vgpr_zero() {
  int z;
  asm volatile("v_mov_b32 %0, 0" : "=v"(z));
  return z;
}

// ---------------------------------------------------------------------------
// K1z: z-run every (b,row) from the fresh state (prev=true -> step 0 gives
// s = x_0 exactly). Output: .x = exit prev (0/1), .y = bitcast(exit state).
// ---------------------------------------------------------------------------
__global__ __launch_bounds__(64, 2) void lif_zrun_kernel(
    const float* __restrict__ x, const float* __restrict__ thresh,
    uint2* __restrict__ zexit) {
  const int wid = blockIdx.x;
  const int b = wid >> 8;
  const int srow = wid & 255;
  const int lane = threadIdx.x;

  const v4f* __restrict__ xr4 =
      (const v4f*)(x + (long)b * kT + srow * kH) + opaque_vgpr_zero();
  v4f xb[32];
#pragma unroll
  for (int i = 0; i < 32; ++i) xb[i] = xr4[i];  // 32 loads in flight

  const float th = thresh[lane];
  float s = 0.0f;
  bool prev = true;  // fresh start: step 0 takes s = x_0

#pragma unroll
  for (int h = 0; h < kH; ++h) {
    const float xt = xb[h >> 2][h & 3];
    const float u = s + xt;
    s = prev ? xt : u;
    prev = s > th;
  }
  uint2 zp;
  zp.x = (unsigned)prev;
  zp.y = __float_as_uint(s);
  zexit[((long)b * kS + srow) * kN + lane] = zp;
}

// ---------------------------------------------------------------------------
// K2v: parallel validation. One wave per (b,row). Entry = A[r] (speculative).
// Writes checkpoint = A[r]; runs ALL 128 steps; dirt iff exit != zexit[r]
// (bitwise). Stores the true exit X[r] only when dirty.
// ---------------------------------------------------------------------------
__global__ __launch_bounds__(64, 2) void lif_validate_kernel(
    const float* __restrict__ x, const float* __restrict__ thresh,
    const float* __restrict__ acc0, const uint2* __restrict__ zexit,
    float* __restrict__ ckpt_s, u64* __restrict__ ckpt_m,
    int* __restrict__ dirt, float* __restrict__ xend_s,
    u64* __restrict__ xend_m) {
  const int wid = blockIdx.x;
  const int b = wid >> 8;
  const int r = wid & 255;
  const int lane = threadIdx.x;
  const long rowi = (long)b * kS + r;

  // speculative entry A[r]
  float s;
  bool p;
  if (r == 0) {
    s = acc0[b * kN + lane];
    p = false;
  } else {
    const uint2 za = zexit[(rowi - 1) * kN + lane];
    s = __uint_as_float(za.y);
    p = za.x != 0u;
  }
  // checkpoint := A[r] (patched later by fixup iff speculation failed)
  ckpt_s[rowi * kN + lane] = s;
  {
    const u64 bm = __ballot(p);
    if (lane == 0) ckpt_m[rowi] = bm;
  }

  const float th = thresh[lane];
  const v4f* __restrict__ xr4 =
      (const v4f*)(x + (long)b * kT + r * kH) + opaque_vgpr_zero();
  v4f xb[32];
#pragma unroll
  for (int i = 0; i < 32; ++i) xb[i] = xr4[i];  // 32 loads in flight

#pragma unroll
  for (int h = 0; h < kH; ++h) {
    const float xt = xb[h >> 2][h & 3];
    const float u = s + xt;
    s = p ? xt : u;
    p = s > th;
  }

  const uint2 zc = zexit[rowi * kN + lane];
  const bool match = (__float_as_uint(s) == zc.y) && (p == (zc.x != 0u));
  if (__all(match)) {
    if (lane == 0) dirt[rowi] = 0;  // clean: exit == A[r+1] exactly
  } else {
    xend_s[rowi * kN + lane] = s;
    const u64 xm = __ballot(p);
    if (lane == 0) {
      xend_m[rowi] = xm;
      dirt[rowi] = 1;
    }
  }
}

// ---------------------------------------------------------------------------
// K3f: fixup. One wave per batch. Loads the 256 dirt flags via 4 lane-
// parallel loads + ballots -> 256-bit bitmap in SGPRs. All clean (virtually
// always) -> return with no further traffic. Else sequential patch-walk:
// adopt X[r] at the first dirty row; while exit != A[r+1], patch the next
// row's checkpoint and re-run it from global x (correct for any data).
// ---------------------------------------------------------------------------
__global__ __launch_bounds__(64, 1) void lif_fixup_kernel(
    const float* __restrict__ x, const float* __restrict__ thresh,
    const uint2* __restrict__ zexit, const int* __restrict__ dirt,
    const float* __restrict__ xend_s, const u64* __restrict__ xend_m,
    float* __restrict__ ckpt_s, u64* __restrict__ ckpt_m) {
  const int b = blockIdx.x;
  const int lane = threadIdx.x;

  u64 dm[4];
#pragma unroll
  for (int k = 0; k < 4; ++k) {
    const int f = dirt[b * kS + k * 64 + lane];
    dm[k] = __ballot(f != 0);
  }
  if ((dm[0] | dm[1] | dm[2] | dm[3]) == 0ULL) return;

  const float th = thresh[lane];
  float s = 0.0f;
  bool p = false;
  bool ok = true;  // true entry of current row == A[r] (speculation holds)

#pragma unroll 1
  for (int r = 0; r < kS; ++r) {
    const bool isd = (dm[r >> 6] >> (r & 63)) & 1ULL;
    const long rowi = (long)b * kS + r;
    if (ok) {
      if (!isd) continue;  // clean + on-track: zero work
      // K2v ran this row from the true entry A[r] -> stored X[r] is truth,
      // and dirty now MEANS X[r] != A[r+1].
      s = xend_s[rowi * kN + lane];
      p = (xend_m[rowi] >> lane) & 1ULL;
      ok = false;
    } else {
      // true entry (s,p) != A[r]: patch checkpoint and re-run this row.
      ckpt_s[rowi * kN + lane] = s;
      {
        const u64 bm = __ballot(p);
        if (lane == 0) ckpt_m[rowi] = bm;
      }
      const v4f* __restrict__ xr4 =
          (const v4f*)(x + (long)b * kT + r * kH) + opaque_vgpr_zero();
      v4f xb[32];
#pragma unroll
      for (int i = 0; i < 32; ++i) xb[i] = xr4[i];
#pragma unroll
      for (int h = 0; h < kH; ++h) {
        const float xt = xb[h >> 2][h & 3];
        const float u = s + xt;
        s = p ? xt : u;
        p = s > th;
      }
      const uint2 zc = zexit[rowi * kN + lane];
      const bool match = (__float_as_uint(s) == zc.y) && (p == (zc.x != 0u));
      ok = __all(match);  // back on the speculative track?
    }
  }
}

// ---------------------------------------------------------------------------
// K4: replay + dense coalesced write (byte-identical to R8..R13 pass2,
// proven absmax = 0). One wave per (b,row); lane = n.
// ---------------------------------------------------------------------------
__global__ __launch_bounds__(64, 2) void lif_pass2_kernel(
    const float* __restrict__ x, const float* __restrict__ thresh,
    const float* __restrict__ ckpt_s, const u64* __restrict__ ckpt_m,
    float* __restrict__ out) {
  const int wid = blockIdx.x;
  const int b = wid >> 8;
  const int srow = wid & 255;
  const int lane = threadIdx.x;

  __shared__ float ov[kH / 2][kN + 1];  // 16.6 KB

  const v4f* __restrict__ xr4 =
      (const v4f*)(x + (long)b * kT + srow * kH) + opaque_vgpr_zero();

  v4f xb[32];
#pragma unroll
  for (int i = 0; i < 32; ++i) xb[i] = xr4[i];  // 32 loads in flight

  const float th = thresh[lane];
  float s = ckpt_s[((long)b * kS + srow) * kN + lane];
  bool prev = (ckpt_m[b * kS + srow] >> lane) & 1ULL;

  float* __restrict__ obase = out + (long)b * kPerB + (long)srow * (kN * kH);
  float* __restrict__ sbase = obase + (long)kB * kPerB;

#pragma unroll
  for (int half = 0; half < 2; ++half) {
#pragma unroll
    for (int hh = 0; hh < kH / 2; ++hh) {
      const int h = half * (kH / 2) + hh;
      const float xt = xb[h >> 2][h & 3];
      const float u = s + xt;
      s = prev ? xt : u;  // bit-identical replay
      prev = s > th;
      ov[hh][lane] = prev ? s : 0.0f;
    }
    const int q = lane & 15;
    const int nsub = lane >> 4;
    const int h0 = half * (kH / 2) + q * 4;
#pragma unroll
    for (int i = 0; i < 16; ++i) {
      const int n = i * 4 + nsub;
      v4f o, sp;
#pragma unroll
      for (int j = 0; j < 4; ++j) {
        const float v = ov[q * 4 + j][n];
        o[j] = v;
        sp[j] = v > 0.0f ? 1.0f : 0.0f;
      }
      *(v4f*)(obase + (long)n * kH + h0) = o;
      *(v4f*)(sbase + (long)n * kH + h0) = sp;
    }
  }
}

// ---------------------------------------------------------------------------
// Fallback A (ws in [1.03MB, 4.08MB)): R8 sequential pass1 + pass2.
// ---------------------------------------------------------------------------
__global__ __launch_bounds__(64, 1) void lif_pass1_kernel(
    const float* __restrict__ x, const float* __restrict__ thresh,
    const float* __restrict__ acc0, float* __restrict__ ckpt_s,
    u64* __restrict__ ckpt_m) {
  const int b = blockIdx.x;
  const int lane = threadIdx.x;
  const float th = thresh[lane];

  __shared__ v4f xs[2048];  // 32 KB: one quarter of this batch's x stream

  const v4f* __restrict__ xg =
      (const v4f*)(x + (long)b * kT) + opaque_vgpr_zero();

  float s = acc0[b * kN + lane];
  bool prev = false;

  float* __restrict__ cs = ckpt_s + (long)b * kS * kN + lane;
  u64* __restrict__ cm = ckpt_m + (long)b * kS;

  for (int q = 0; q < 4; ++q) {
    {
      const v4f* __restrict__ src = xg + (long)q * 2048 + lane;
      v4f tmp[32];
#pragma unroll
      for (int i = 0; i < 32; ++i) tmp[i] = src[i * 64];
#pragma unroll
      for (int i = 0; i < 32; ++i) xs[i * 64 + lane] = tmp[i];
    }
    for (int jrow = 0; jrow < 64; ++jrow) {
      const int r = q * 64 + jrow;
      cs[(long)r * kN] = s;
      {
        const u64 m = __ballot(prev);
        if (lane == 0) cm[r] = m;
      }
      const v4f* __restrict__ xr = &xs[jrow * 32];
#pragma unroll
      for (int k = 0; k < 32; ++k) {
        const v4f xv = xr[k];
#pragma unroll
        for (int j = 0; j < 4; ++j) {
          const float xt = xv[j];
          const float u = s + xt;
          s = prev ? xt : u;
          prev = s > th;
        }
      }
    }
  }
}

// ---------------------------------------------------------------------------
// Fallback B (tiny ws): R4's passing fused kernel (unchanged).
// ---------------------------------------------------------------------------
__global__ __launch_bounds__(128) void lif_fused_kernel(
    const float* __restrict__ x, const float* __restrict__ thresh,
    const float* __restrict__ acc0, float* __restrict__ out) {
  const int bid = blockIdx.x;
  const int b = bid >> 2;
  const int ng = bid & 3;
  const int tid = threadIdx.x;
  const int wave = tid >> 6;
  const int lane = tid & 63;
  __shared__ float buf[2][kH][64];
  const float* __restrict__ xb = x + (long)b * kT;
  float* __restrict__ outs_g = out + (long)b * kPerB + (long)(ng * 16) * kH;
  float* __restrict__ spks_g = outs_g + (long)kB * kPerB;
  if (wave == 0) {
    const int n = lane & 15;
    const float th = thresh[ng * 16 + n];
    float s = acc0[b * kN + ng * 16 + n];
    bool prev = false;
    for (int r = 0; r < kS + 1; ++r) {
      if (r < kS) {
        float* __restrict__ bk = &buf[r & 1][0][lane];
        const float* __restrict__ xr = xb + r * kH;
#pragma unroll
        for (int k = 0; k < kH; ++k) {
          const float xt = xr[k];
          const float u = s + xt;
          s = prev ? xt : u;
          prev = s > th;
          bk[k * 64] = s;
        }
      }
      __syncthreads();
    }
  } else {
    const int n = lane >> 2;
    const int hg = lane & 3;
    const float th = thresh[ng * 16 + n];
    for (int r = 0; r < kS + 1; ++r) {
      if (r > 0) {
        const int rr = r - 1;
        const float(*bk)[64] = buf[rr & 1];
        float* __restrict__ orow = outs_g + (long)rr * (kN * kH) + n * kH;
        float* __restrict__ srow = spks_g + (long)rr * (kN * kH) + n * kH;
#pragma unroll
        for (int i = 0; i < 8; ++i) {
          const int hh = hg * 4 + i * 16;
          v4f ovv, sv;
#pragma unroll
          for (int j = 0; j < 4; ++j) {
            const float v = bk[hh + j][n];
            const bool sp = v > th;
            ovv[j] = sp ? v : 0.0f;
            sv[j] = sp ? 1.0f : 0.0f;
          }
          *(v4f*)(orow + hh) = ovv;
          *(v4f*)(srow + hh) = sv;
        }
      }
      __syncthreads();
    }
  }
}

// ---------------------------------------------------------------------------
extern "C" void kernel_launch(void* const* d_in, const int* in_sizes, int n_in,
                              void* d_out, int out_size, void* d_ws, size_t ws_size,
                              hipStream_t stream) {
  const float* inputs = (const float*)d_in[0];    // [B,S,H] fp32
  const float* threshes = (const float*)d_in[1];  // [N] fp32
  const float* acc0 = (const float*)d_in[2];      // [B,N] fp32
  float* out = (float*)d_out;

  if (ws_size >= kWsZp + kWsS + kWsM + kWsD + kWsXs + kWsXm) {
    char* p = (char*)d_ws;
    uint2* zexitp = (uint2*)p;            p += kWsZp;
    float* ckpt_s = (float*)p;            p += kWsS;
    u64* ckpt_m = (u64*)p;                p += kWsM;
    int* dirt = (int*)p;                  p += kWsD;
    float* xend_s = (float*)p;            p += kWsXs;
    u64* xend_m = (u64*)p;
    lif_zrun_kernel<<<kB * kS, kN, 0, stream>>>(inputs, threshes, zexitp);
    lif_validate_kernel<<<kB * kS, kN, 0, stream>>>(
        inputs, threshes, acc0, zexitp, ckpt_s, ckpt_m, dirt, xend_s, xend_m);
    lif_fixup_kernel<<<kB, kN, 0, stream>>>(inputs, threshes, zexitp, dirt,
                                            xend_s, xend_m, ckpt_s, ckpt_m);
    lif_pass2_kernel<<<kB * kS, kN, 0, stream>>>(inputs, threshes, ckpt_s,
                                                 ckpt_m, out);
  } else if (ws_size >= kWsS + kWsM) {
    float* ckpt_s = (float*)d_ws;
    u64* ckpt_m = (u64*)((char*)d_ws + kWsS);
    lif_pass1_kernel<<<kB, kN, 0, stream>>>(inputs, threshes, acc0, ckpt_s,
                                            ckpt_m);
    lif_pass2_kernel<<<kB * kS, kN, 0, stream>>>(inputs, threshes, ckpt_s,
                                                 ckpt_m, out);
  } else {
    lif_fused_kernel<<<kB * 4, 128, 0, stream>>>(inputs, threshes, acc0, out);
  }
}

// Round 9
// 591.685 us; speedup vs baseline: 1.3027x; 1.1821x over previous
//
#include <hip/hip_runtime.h>

// LIF scan: B=16, S=256, H=128, N=64. T = S*H = 32768 sequential steps per
// (b,n) chain; 1024 chains. Bit-exactness with the fp32 sequential reference
// required -> add chain cannot be reassociated. Chain form (proven bit-exact
// R6..R14):   s' = prev ? x : fl(s + x);  prev' = s' > th
//
// R16 = R15 resubmitted byte-identical: the R15 bench died with "container
// failed twice" (infra acquisition failure, no compile error, no counters) —
// same signature as R11, which ran fine when resubmitted unchanged (R12).
// Kernel re-audited: single-wave blocks (no barrier hazard), all LDS indices
// bounded, finite loops; no kernel-side kill mechanism identified.
//
// R15: abandon speculative coalescence (R9-R14). R14's fixup WRITE_SIZE
// (976KB = full ckpt rewrite) proves the true chain fails to merge bitwise
// with the fresh run on ~45% of rows (high-th lanes: inter-spike state is a
// random walk; P(no crossing of th~0.99 in a row) ~14%). Any merge-based
// scheme leaves a serial cleanup chain -> 400-500us forever.
//
// Back to EXACT full re-simulation (R8 structure), fixing its one real
// defect: R8 = 27.7 cyc/step because each quad's ds_read sat in the dep
// chain (compiler sinks LDS reads to use; VGPR=88 proved it). Fix per the
// ISA-guide-proven recipe: __builtin_amdgcn_sched_barrier(0) fences around
// an explicit 4-buffer static rotation (use group k, prefetch group k+2).
// sched_barrier(0) forbids code motion -> reads stay issued one full group
// body (~130cyc) ahead of use (~120cyc LDS latency). Flat group index
// across row boundaries -> no per-row prologue stall. Target ~8-10
// cyc/step = 110-150us for the whole chain pass.
//
// Pass2: BYTE-IDENTICAL to R8..R14 (proven absmax=0 six times).

namespace {
constexpr int kB = 16;
constexpr int kS = 256;
constexpr int kH = 128;
constexpr int kN = 64;
constexpr int kT = kS * kH;                 // 32768
constexpr long kPerB = (long)kS * kN * kH;  // 2,097,152 per batch per tensor
// ws layout: ckpt_s | ckpt_m
constexpr size_t kWsS = (size_t)kB * kS * kN * sizeof(float);          // 1 MB
constexpr size_t kWsM = (size_t)kB * kS * sizeof(unsigned long long);  // 32 KB
}

typedef float v4f __attribute__((ext_vector_type(4)));
typedef unsigned long long u64;

// Opaque VGPR zero: defeats uniform-scalarization so wave-uniform-looking
// loads use the vector path (vmcnt, in-order) instead of SMEM s_loads
// (lgkmcnt, unordered -> full drains). Proven effective in R6.
__device__ __forceinline__ int opaque_vgpr_zero() {
  int z;
  asm volatile("v_mov_b32 %0, 0" : "=v"(z));
  return z;
}

// 4 chain steps from one resident v4f. Critical path per step: v_add_f32 ->
// v_cndmask (prev's v_cmp is off-path, consumed next step) ~ 8 cyc.
__device__ __forceinline__ void chain4(const v4f xv, float& s, bool& prev,
                                       const float th) {
#pragma unroll
  for (int t = 0; t < 4; ++t) {
    const float xt = xv[t];
    const float u = s + xt;   // dep-chain op 1
    s = prev ? xt : u;        // dep-chain op 2 (cndmask)
    prev = s > th;            // off-chain cmp
  }
}

// ---------------------------------------------------------------------------
// K1: the sequential chains, exact. block = batch, lane = neuron. x staged
// into LDS in 32KB quarters (R8's proven staging); consume via a 4-buffer
// static register rotation with sched_barrier(0) fences: group k's 16 steps
// run while group k+2's 4 ds_reads are in flight. Checkpoints (entering
// state s + ballot(prev)) at every row.
// ---------------------------------------------------------------------------
__global__ __launch_bounds__(64, 1) void lif_chain_kernel(
    const float* __restrict__ x, const float* __restrict__ thresh,
    const float* __restrict__ acc0, float* __restrict__ ckpt_s,
    u64* __restrict__ ckpt_m) {
  const int b = blockIdx.x;
  const int lane = threadIdx.x;
  const float th = thresh[lane];

  __shared__ v4f xs4[2048];  // 32 KB: one quarter (64 rows) of this batch

  const v4f* __restrict__ xg =
      (const v4f*)(x + (long)b * kT) + opaque_vgpr_zero();

  float s = acc0[b * kN + lane];
  bool prev = false;

  float* __restrict__ cs = ckpt_s + (long)b * kS * kN + lane;
  u64* __restrict__ cm = ckpt_m + (long)b * kS;

#pragma unroll 1
  for (int q = 0; q < 4; ++q) {
    // ---- stage quarter q (R8 proven pattern: 32 loads in flight, then 32
    // contiguous ds_writes; single wave -> DS in-order, no barrier needed)
    {
      const v4f* __restrict__ src = xg + (long)q * 2048 + lane;
      v4f tmp[32];
#pragma unroll
      for (int i = 0; i < 32; ++i) tmp[i] = src[i * 64];
#pragma unroll
      for (int i = 0; i < 32; ++i) xs4[i * 64 + lane] = tmp[i];
    }

    // ---- consume: 512 flat groups (64 rows x 8 groups of 16 steps).
    // Static 4-set rotation A,B,C,D: group k consumes set (k%4), group k
    // prefetches flat-group gq+2 into set ((k+2)%4).
    v4f A0, A1, A2, A3, B0, B1, B2, B3;
    v4f C0, C1, C2, C3, D0, D1, D2, D3;
    A0 = xs4[0]; A1 = xs4[1]; A2 = xs4[2]; A3 = xs4[3];  // group 0
    B0 = xs4[4]; B1 = xs4[5]; B2 = xs4[6]; B3 = xs4[7];  // group 1
    __builtin_amdgcn_sched_barrier(0);

#define LIF_GROUP(U0, U1, U2, U3, P0, P1, P2, P3, OFS)                  \
  {                                                                     \
    const int pf = (gq + (OFS) <= 511) ? (gq + (OFS)) : 511;            \
    P0 = xs4[4 * pf + 0];                                               \
    P1 = xs4[4 * pf + 1];                                               \
    P2 = xs4[4 * pf + 2];                                               \
    P3 = xs4[4 * pf + 3];                                               \
    __builtin_amdgcn_sched_barrier(0);                                  \
    chain4(U0, s, prev, th);                                            \
    chain4(U1, s, prev, th);                                            \
    chain4(U2, s, prev, th);                                            \
    chain4(U3, s, prev, th);                                            \
    __builtin_amdgcn_sched_barrier(0);                                  \
  }

#pragma unroll 1
    for (int j = 0; j < 64; ++j) {
      const int r = q * 64 + j;
      // checkpoint: entering state
      cs[(long)r * kN] = s;
      {
        const u64 m = __ballot(prev);
        if (lane == 0) cm[r] = m;
      }
      const int gq = j * 8;
      LIF_GROUP(A0, A1, A2, A3, C0, C1, C2, C3, 2)  // k=0: use A, pf->C
      LIF_GROUP(B0, B1, B2, B3, D0, D1, D2, D3, 3)  // k=1: use B, pf->D
      LIF_GROUP(C0, C1, C2, C3, A0, A1, A2, A3, 4)  // k=2: use C, pf->A
      LIF_GROUP(D0, D1, D2, D3, B0, B1, B2, B3, 5)  // k=3: use D, pf->B
      LIF_GROUP(A0, A1, A2, A3, C0, C1, C2, C3, 6)  // k=4
      LIF_GROUP(B0, B1, B2, B3, D0, D1, D2, D3, 7)  // k=5
      LIF_GROUP(C0, C1, C2, C3, A0, A1, A2, A3, 8)  // k=6: pf next row g0
      LIF_GROUP(D0, D1, D2, D3, B0, B1, B2, B3, 9)  // k=7: pf next row g1
    }
#undef LIF_GROUP
    // invariant: A,B hold next quarter's stale data; prologue reloads after
    // restaging. All ds_reads retired before the staging ds_writes of the
    // next quarter (DS pipe in-order per wave).
  }
}

// ---------------------------------------------------------------------------
// K2: replay + dense coalesced write (byte-identical to R8..R14 pass2,
// proven absmax = 0). One wave per (b,row); lane = n.
// ---------------------------------------------------------------------------
__global__ __launch_bounds__(64, 2) void lif_pass2_kernel(
    const float* __restrict__ x, const float* __restrict__ thresh,
    const float* __restrict__ ckpt_s, const u64* __restrict__ ckpt_m,
    float* __restrict__ out) {
  const int wid = blockIdx.x;
  const int b = wid >> 8;
  const int srow = wid & 255;
  const int lane = threadIdx.x;

  __shared__ float ov[kH / 2][kN + 1];  // 16.6 KB

  const v4f* __restrict__ xr4 =
      (const v4f*)(x + (long)b * kT + srow * kH) + opaque_vgpr_zero();

  v4f xb[32];
#pragma unroll
  for (int i = 0; i < 32; ++i) xb[i] = xr4[i];  // 32 loads in flight

  const float th = thresh[lane];
  float s = ckpt_s[((long)b * kS + srow) * kN + lane];
  bool prev = (ckpt_m[b * kS + srow] >> lane) & 1ULL;

  float* __restrict__ obase = out + (long)b * kPerB + (long)srow * (kN * kH);
  float* __restrict__ sbase = obase + (long)kB * kPerB;

#pragma unroll
  for (int half = 0; half < 2; ++half) {
#pragma unroll
    for (int hh = 0; hh < kH / 2; ++hh) {
      const int h = half * (kH / 2) + hh;
      const float xt = xb[h >> 2][h & 3];
      const float u = s + xt;
      s = prev ? xt : u;  // bit-identical replay
      prev = s > th;
      ov[hh][lane] = prev ? s : 0.0f;
    }
    const int q = lane & 15;
    const int nsub = lane >> 4;
    const int h0 = half * (kH / 2) + q * 4;
#pragma unroll
    for (int i = 0; i < 16; ++i) {
      const int n = i * 4 + nsub;
      v4f o, sp;
#pragma unroll
      for (int j = 0; j < 4; ++j) {
        const float v = ov[q * 4 + j][n];
        o[j] = v;
        sp[j] = v > 0.0f ? 1.0f : 0.0f;
      }
      *(v4f*)(obase + (long)n * kH + h0) = o;
      *(v4f*)(sbase + (long)n * kH + h0) = sp;
    }
  }
}

// ---------------------------------------------------------------------------
// Fallback (tiny ws): R4's passing fused kernel (unchanged).
// ---------------------------------------------------------------------------
__global__ __launch_bounds__(128) void lif_fused_kernel(
    const float* __restrict__ x, const float* __restrict__ thresh,
    const float* __restrict__ acc0, float* __restrict__ out) {
  const int bid = blockIdx.x;
  const int b = bid >> 2;
  const int ng = bid & 3;
  const int tid = threadIdx.x;
  const int wave = tid >> 6;
  const int lane = tid & 63;
  __shared__ float buf[2][kH][64];
  const float* __restrict__ xb = x + (long)b * kT;
  float* __restrict__ outs_g = out + (long)b * kPerB + (long)(ng * 16) * kH;
  float* __restrict__ spks_g = outs_g + (long)kB * kPerB;
  if (wave == 0) {
    const int n = lane & 15;
    const float th = thresh[ng * 16 + n];
    float s = acc0[b * kN + ng * 16 + n];
    bool prev = false;
    for (int r = 0; r < kS + 1; ++r) {
      if (r < kS) {
        float* __restrict__ bk = &buf[r & 1][0][lane];
        const float* __restrict__ xr = xb + r * kH;
#pragma unroll
        for (int k = 0; k < kH; ++k) {
          const float xt = xr[k];
          const float u = s + xt;
          s = prev ? xt : u;
          prev = s > th;
          bk[k * 64] = s;
        }
      }
      __syncthreads();
    }
  } else {
    const int n = lane >> 2;
    const int hg = lane & 3;
    const float th = thresh[ng * 16 + n];
    for (int r = 0; r < kS + 1; ++r) {
      if (r > 0) {
        const int rr = r - 1;
        const float(*bk)[64] = buf[rr & 1];
        float* __restrict__ orow = outs_g + (long)rr * (kN * kH) + n * kH;
        float* __restrict__ srow = spks_g + (long)rr * (kN * kH) + n * kH;
#pragma unroll
        for (int i = 0; i < 8; ++i) {
          const int hh = hg * 4 + i * 16;
          v4f ovv, sv;
#pragma unroll
          for (int j = 0; j < 4; ++j) {
            const float v = bk[hh + j][n];
            const bool sp = v > th;
            ovv[j] = sp ? v : 0.0f;
            sv[j] = sp ? 1.0f : 0.0f;
          }
          *(v4f*)(orow + hh) = ovv;
          *(v4f*)(srow + hh) = sv;
        }
      }
      __syncthreads();
    }
  }
}

// ---------------------------------------------------------------------------
extern "C" void kernel_launch(void* const* d_in, const int* in_sizes, int n_in,
                              void* d_out, int out_size, void* d_ws, size_t ws_size,
                              hipStream_t stream) {
  const float* inputs = (const float*)d_in[0];    // [B,S,H] fp32
  const float* threshes = (const float*)d_in[1];  // [N] fp32
  const float* acc0 = (const float*)d_in[2];      // [B,N] fp32
  float* out = (float*)d_out;

  if (ws_size >= kWsS + kWsM) {
    float* ckpt_s = (float*)d_ws;
    u64* ckpt_m = (u64*)((char*)d_ws + kWsS);
    lif_chain_kernel<<<kB, kN, 0, stream>>>(inputs, threshes, acc0, ckpt_s,
                                            ckpt_m);
    lif_pass2_kernel<<<kB * kS, kN, 0, stream>>>(inputs, threshes, ckpt_s,
                                                 ckpt_m, out);
  } else {
    lif_fused_kernel<<<kB * 4, 128, 0, stream>>>(inputs, threshes, acc0, out);
  }
}

// Round 11
// 483.575 us; speedup vs baseline: 1.5939x; 1.2236x over previous
//
#include <hip/hip_runtime.h>

// LIF scan: B=16, S=256, H=128, N=64. T = S*H = 32768 sequential steps per
// (b,n) chain; 1024 chains. Bit-exactness with the fp32 sequential reference
// required -> add chain cannot be reassociated. Chain form (proven bit-exact
// R6..R16):   s' = prev ? x : fl(s + x);  prev' = s' > th
//
// R18: rerun R17's decisive H1/H2 experiment with boring encodings. R17
// (prev held via "+s" SGPR-pair asm operand) died with a runtime abort —
// the only delta vs passing R16 was the asm, prime suspect the unusual
// SGPR-pair constraint. This version holds prev in VCC (the canonical mask
// reg), entering/leaving each 16-step asm block via a 0/1 int VGPR:
//   entry:  v_cmp_ne_u32 vcc, 0, pv
//   step:   v_add_f32 t,s,x ; v_cndmask_b32 s,t,x,vcc ; v_cmp_gt_f32 vcc,s,th
//   exit:   v_cndmask_b32 pv, 0, 1, vcc      (0/1 inline consts, VOP3-legal)
// vcc clobbered; every instruction is a verbatim cdna4_isa.md row.
//
// Question under test: R16 = 24.6 cyc/step on a 2-dep-edge cycle. H1 =
// lone-wave dependent-VALU latency ~12 cyc (R16 is the HW floor; total 591us
// is structural). H2 = latency ~4-6 cyc, rest is compiler slack on the chain
// (i1 prev materialization etc.) -> this kernel lands 160-220us for pass1.
//
// Staging, 4-buffer rotation, sched_barrier(0) fences, checkpoints, pass2:
// byte-identical to R16 (passed, absmax=0).

namespace {
constexpr int kB = 16;
constexpr int kS = 256;
constexpr int kH = 128;
constexpr int kN = 64;
constexpr int kT = kS * kH;                 // 32768
constexpr long kPerB = (long)kS * kN * kH;  // 2,097,152 per batch per tensor
// ws layout: ckpt_s | ckpt_m
constexpr size_t kWsS = (size_t)kB * kS * kN * sizeof(float);          // 1 MB
constexpr size_t kWsM = (size_t)kB * kS * sizeof(unsigned long long);  // 32 KB
}

typedef float v4f __attribute__((ext_vector_type(4)));
typedef unsigned long long u64;

// Opaque VGPR zero: defeats uniform-scalarization so wave-uniform-looking
// loads use the vector path (vmcnt, in-order) instead of SMEM s_loads
// (lgkmcnt, unordered -> full drains). Proven effective in R6.
__device__ __forceinline__ int opaque_vgpr_zero() {
  int z;
  asm volatile("v_mov_b32 %0, 0" : "=v"(z));
  return z;
}

// One chain step, exact ISA form, prev in vcc. Order matters: cndmask
// consumes OLD vcc, cmp then overwrites vcc for the next step.
#define LIF_STEP_ASM(XN)                              \
  "v_add_f32 %[t], %[s], %[" XN "]\n\t"               \
  "v_cndmask_b32 %[s], %[t], %[" XN "], vcc\n\t"      \
  "v_cmp_gt_f32 vcc, %[s], %[th]\n\t"

// 16 steps (4 quads) as a single asm block. pv: 0/1 int VGPR carrying prev
// across blocks; vcc live only inside the block (clobbered).
#define CHAIN16(Q0, Q1, Q2, Q3)                                             \
  {                                                                         \
    float tmp_;                                                             \
    asm volatile(                                                           \
        "v_cmp_ne_u32 vcc, 0, %[pv]\n\t"                                    \
        LIF_STEP_ASM("xa0") LIF_STEP_ASM("xa1")                             \
        LIF_STEP_ASM("xa2") LIF_STEP_ASM("xa3")                             \
        LIF_STEP_ASM("xb0") LIF_STEP_ASM("xb1")                             \
        LIF_STEP_ASM("xb2") LIF_STEP_ASM("xb3")                             \
        LIF_STEP_ASM("xc0") LIF_STEP_ASM("xc1")                             \
        LIF_STEP_ASM("xc2") LIF_STEP_ASM("xc3")                             \
        LIF_STEP_ASM("xd0") LIF_STEP_ASM("xd1")                             \
        LIF_STEP_ASM("xd2") LIF_STEP_ASM("xd3")                             \
        "v_cndmask_b32 %[pv], 0, 1, vcc\n\t"                                \
        : [s] "+v"(s), [pv] "+v"(pv), [t] "=&v"(tmp_)                       \
        : [xa0] "v"((Q0)[0]), [xa1] "v"((Q0)[1]),                           \
          [xa2] "v"((Q0)[2]), [xa3] "v"((Q0)[3]),                           \
          [xb0] "v"((Q1)[0]), [xb1] "v"((Q1)[1]),                           \
          [xb2] "v"((Q1)[2]), [xb3] "v"((Q1)[3]),                           \
          [xc0] "v"((Q2)[0]), [xc1] "v"((Q2)[1]),                           \
          [xc2] "v"((Q2)[2]), [xc3] "v"((Q2)[3]),                           \
          [xd0] "v"((Q3)[0]), [xd1] "v"((Q3)[1]),                           \
          [xd2] "v"((Q3)[2]), [xd3] "v"((Q3)[3]), [th] "v"(th)              \
        : "vcc");                                                           \
  }

// ---------------------------------------------------------------------------
// K1: the sequential chains, exact. block = batch, lane = neuron. x staged
// into LDS in 32KB quarters; 4-buffer static rotation + sched_barrier(0)
// fences (R16 structure); 16-step asm chain groups with prev in vcc.
// Checkpoints (entering state s + ballot(prev)) at every row.
// ---------------------------------------------------------------------------
__global__ __launch_bounds__(64, 1) void lif_chain_kernel(
    const float* __restrict__ x, const float* __restrict__ thresh,
    const float* __restrict__ acc0, float* __restrict__ ckpt_s,
    u64* __restrict__ ckpt_m) {
  const int b = blockIdx.x;
  const int lane = threadIdx.x;
  const float th = thresh[lane];

  __shared__ v4f xs4[2048];  // 32 KB: one quarter (64 rows) of this batch

  const v4f* __restrict__ xg =
      (const v4f*)(x + (long)b * kT) + opaque_vgpr_zero();

  float s = acc0[b * kN + lane];
  int pv = 0;  // prev as 0/1 (false at t=0)

  float* __restrict__ cs = ckpt_s + (long)b * kS * kN + lane;
  u64* __restrict__ cm = ckpt_m + (long)b * kS;

#pragma unroll 1
  for (int q = 0; q < 4; ++q) {
    // ---- stage quarter q (proven pattern: 32 loads in flight, then 32
    // contiguous ds_writes; single wave -> DS in-order, no barrier needed)
    {
      const v4f* __restrict__ src = xg + (long)q * 2048 + lane;
      v4f tmp[32];
#pragma unroll
      for (int i = 0; i < 32; ++i) tmp[i] = src[i * 64];
#pragma unroll
      for (int i = 0; i < 32; ++i) xs4[i * 64 + lane] = tmp[i];
    }

    // ---- consume: 512 flat groups (64 rows x 8 groups of 16 steps).
    // Static 4-set rotation A,B,C,D: group k consumes set (k%4), group k
    // prefetches flat-group gq+2 into set ((k+2)%4).
    v4f A0, A1, A2, A3, B0, B1, B2, B3;
    v4f C0, C1, C2, C3, D0, D1, D2, D3;
    A0 = xs4[0]; A1 = xs4[1]; A2 = xs4[2]; A3 = xs4[3];  // group 0
    B0 = xs4[4]; B1 = xs4[5]; B2 = xs4[6]; B3 = xs4[7];  // group 1
    __builtin_amdgcn_sched_barrier(0);

#define LIF_GROUP(U0, U1, U2, U3, P0, P1, P2, P3, OFS)                  \
  {                                                                     \
    const int pf = (gq + (OFS) <= 511) ? (gq + (OFS)) : 511;            \
    P0 = xs4[4 * pf + 0];                                               \
    P1 = xs4[4 * pf + 1];                                               \
    P2 = xs4[4 * pf + 2];                                               \
    P3 = xs4[4 * pf + 3];                                               \
    __builtin_amdgcn_sched_barrier(0);                                  \
    CHAIN16(U0, U1, U2, U3)                                             \
    __builtin_amdgcn_sched_barrier(0);                                  \
  }

#pragma unroll 1
    for (int j = 0; j < 64; ++j) {
      const int r = q * 64 + j;
      // checkpoint: entering state
      cs[(long)r * kN] = s;
      {
        const u64 m = __ballot(pv != 0);
        if (lane == 0) cm[r] = m;
      }
      const int gq = j * 8;
      LIF_GROUP(A0, A1, A2, A3, C0, C1, C2, C3, 2)  // k=0: use A, pf->C
      LIF_GROUP(B0, B1, B2, B3, D0, D1, D2, D3, 3)  // k=1: use B, pf->D
      LIF_GROUP(C0, C1, C2, C3, A0, A1, A2, A3, 4)  // k=2: use C, pf->A
      LIF_GROUP(D0, D1, D2, D3, B0, B1, B2, B3, 5)  // k=3: use D, pf->B
      LIF_GROUP(A0, A1, A2, A3, C0, C1, C2, C3, 6)  // k=4
      LIF_GROUP(B0, B1, B2, B3, D0, D1, D2, D3, 7)  // k=5
      LIF_GROUP(C0, C1, C2, C3, A0, A1, A2, A3, 8)  // k=6: pf next row g0
      LIF_GROUP(D0, D1, D2, D3, B0, B1, B2, B3, 9)  // k=7: pf next row g1
    }
#undef LIF_GROUP
    // invariant: A,B hold next quarter's stale data; prologue reloads after
    // restaging. All ds_reads retired before the staging ds_writes of the
    // next quarter (DS pipe in-order per wave).
  }
}

// ---------------------------------------------------------------------------
// K2: replay + dense coalesced write (byte-identical to R8..R16 pass2,
// proven absmax = 0). One wave per (b,row); lane = n.
// ---------------------------------------------------------------------------
__global__ __launch_bounds__(64, 2) void lif_pass2_kernel(
    const float* __restrict__ x, const float* __restrict__ thresh,
    const float* __restrict__ ckpt_s, const u64* __restrict__ ckpt_m,
    float* __restrict__ out) {
  const int wid = blockIdx.x;
  const int b = wid >> 8;
  const int srow = wid & 255;
  const int lane = threadIdx.x;

  __shared__ float ov[kH / 2][kN + 1];  // 16.6 KB

  const v4f* __restrict__ xr4 =
      (const v4f*)(x + (long)b * kT + srow * kH) + opaque_vgpr_zero();

  v4f xb[32];
#pragma unroll
  for (int i = 0; i < 32; ++i) xb[i] = xr4[i];  // 32 loads in flight

  const float th = thresh[lane];
  float s = ckpt_s[((long)b * kS + srow) * kN + lane];
  bool prev = (ckpt_m[b * kS + srow] >> lane) & 1ULL;

  float* __restrict__ obase = out + (long)b * kPerB + (long)srow * (kN * kH);
  float* __restrict__ sbase = obase + (long)kB * kPerB;

#pragma unroll
  for (int half = 0; half < 2; ++half) {
#pragma unroll
    for (int hh = 0; hh < kH / 2; ++hh) {
      const int h = half * (kH / 2) + hh;
      const float xt = xb[h >> 2][h & 3];
      const float u = s + xt;
      s = prev ? xt : u;  // bit-identical replay
      prev = s > th;
      ov[hh][lane] = prev ? s : 0.0f;
    }
    const int q = lane & 15;
    const int nsub = lane >> 4;
    const int h0 = half * (kH / 2) + q * 4;
#pragma unroll
    for (int i = 0; i < 16; ++i) {
      const int n = i * 4 + nsub;
      v4f o, sp;
#pragma unroll
      for (int j = 0; j < 4; ++j) {
        const float v = ov[q * 4 + j][n];
        o[j] = v;
        sp[j] = v > 0.0f ? 1.0f : 0.0f;
      }
      *(v4f*)(obase + (long)n * kH + h0) = o;
      *(v4f*)(sbase + (long)n * kH + h0) = sp;
    }
  }
}

// ---------------------------------------------------------------------------
// Fallback (tiny ws): R4's passing fused kernel (unchanged).
// ---------------------------------------------------------------------------
__global__ __launch_bounds__(128) void lif_fused_kernel(
    const float* __restrict__ x, const float* __restrict__ thresh,
    const float* __restrict__ acc0, float* __restrict__ out) {
  const int bid = blockIdx.x;
  const int b = bid >> 2;
  const int ng = bid & 3;
  const int tid = threadIdx.x;
  const int wave = tid >> 6;
  const int lane = tid & 63;
  __shared__ float buf[2][kH][64];
  const float* __restrict__ xb = x + (long)b * kT;
  float* __restrict__ outs_g = out + (long)b * kPerB + (long)(ng * 16) * kH;
  float* __restrict__ spks_g = outs_g + (long)kB * kPerB;
  if (wave == 0) {
    const int n = lane & 15;
    const float th = thresh[ng * 16 + n];
    float s = acc0[b * kN + ng * 16 + n];
    bool prev = false;
    for (int r = 0; r < kS + 1; ++r) {
      if (r < kS) {
        float* __restrict__ bk = &buf[r & 1][0][lane];
        const float* __restrict__ xr = xb + r * kH;
#pragma unroll
        for (int k = 0; k < kH; ++k) {
          const float xt = xr[k];
          const float u = s + xt;
          s = prev ? xt : u;
          prev = s > th;
          bk[k * 64] = s;
        }
      }
      __syncthreads();
    }
  } else {
    const int n = lane >> 2;
    const int hg = lane & 3;
    const float th = thresh[ng * 16 + n];
    for (int r = 0; r < kS + 1; ++r) {
      if (r > 0) {
        const int rr = r - 1;
        const float(*bk)[64] = buf[rr & 1];
        float* __restrict__ orow = outs_g + (long)rr * (kN * kH) + n * kH;
        float* __restrict__ srow = spks_g + (long)rr * (kN * kH) + n * kH;
#pragma unroll
        for (int i = 0; i < 8; ++i) {
          const int hh = hg * 4 + i * 16;
          v4f ovv, sv;
#pragma unroll
          for (int j = 0; j < 4; ++j) {
            const float v = bk[hh + j][n];
            const bool sp = v > th;
            ovv[j] = sp ? v : 0.0f;
            sv[j] = sp ? 1.0f : 0.0f;
          }
          *(v4f*)(orow + hh) = ovv;
          *(v4f*)(srow + hh) = sv;
        }
      }
      __syncthreads();
    }
  }
}

// ---------------------------------------------------------------------------
extern "C" void kernel_launch(void* const* d_in, const int* in_sizes, int n_in,
                              void* d_out, int out_size, void* d_ws, size_t ws_size,
                              hipStream_t stream) {
  const float* inputs = (const float*)d_in[0];    // [B,S,H] fp32
  const float* threshes = (const float*)d_in[1];  // [N] fp32
  const float* acc0 = (const float*)d_in[2];      // [B,N] fp32
  float* out = (float*)d_out;

  if (ws_size >= kWsS + kWsM) {
    float* ckpt_s = (float*)d_ws;
    u64* ckpt_m = (u64*)((char*)d_ws + kWsS);
    lif_chain_kernel<<<kB, kN, 0, stream>>>(inputs, threshes, acc0, ckpt_s,
                                            ckpt_m);
    lif_pass2_kernel<<<kB * kS, kN, 0, stream>>>(inputs, threshes, ckpt_s,
                                                 ckpt_m, out);
  } else {
    lif_fused_kernel<<<kB * 4, 128, 0, stream>>>(inputs, threshes, acc0, out);
  }
}